// Round 3
// baseline (95.927 us; speedup 1.0000x reference)
//
#include <hip/hip_runtime.h>
#include <cmath>

#define NF 4096
#define PI2F 6.2831853071795864769f

typedef float2 cf;

__device__ __forceinline__ cf cmulf(cf a, cf b){
  return make_float2(fmaf(a.x, b.x, -(a.y*b.y)), fmaf(a.x, b.y, a.y*b.x));
}

// zero-size-overhead LDS swizzle: XOR low digit with next digit.
// Keeps stride-256, stride-16 and contiguous-16 wave accesses all at the
// b64 4-bank-cycle floor; LDS stays exactly 4096 cf = 32 KiB -> 5 blocks/CU.
__device__ __forceinline__ int phys(int i){ return i ^ ((i >> 4) & 15); }

// radix-16 DFT in registers; INV=0 forward (e^{-i}), INV=1 inverse (e^{+i}), unnormalized.
template<int INV>
__device__ __forceinline__ void dft16(cf* v){
  const float C1 = 0.9238795325112867f;
  const float S1 = 0.3826834323650898f;
  const float HF = 0.7071067811865476f;
  cf c[16];
#pragma unroll
  for (int q1 = 0; q1 < 4; ++q1){
    cf a = v[q1], b = v[q1+4], d = v[q1+8], e = v[q1+12];
    cf t0 = make_float2(a.x+d.x, a.y+d.y);
    cf t1 = make_float2(a.x-d.x, a.y-d.y);
    cf t2 = make_float2(b.x+e.x, b.y+e.y);
    cf t3 = make_float2(b.x-e.x, b.y-e.y);
    c[q1*4+0] = make_float2(t0.x+t2.x, t0.y+t2.y);
    c[q1*4+2] = make_float2(t0.x-t2.x, t0.y-t2.y);
    if (!INV){
      c[q1*4+1] = make_float2(t1.x+t3.y, t1.y-t3.x);   // t1 - i t3
      c[q1*4+3] = make_float2(t1.x-t3.y, t1.y+t3.x);   // t1 + i t3
    } else {
      c[q1*4+1] = make_float2(t1.x-t3.y, t1.y+t3.x);
      c[q1*4+3] = make_float2(t1.x+t3.y, t1.y-t3.x);
    }
  }
  // internal twiddles w16^{q1*r0} (conjugated for inverse)
  {
    auto tw = [&](int i, float wr, float wi){
      float wii = INV ? -wi : wi;
      cf z = c[i];
      c[i] = make_float2(fmaf(z.x, wr, -(z.y*wii)), fmaf(z.x, wii, z.y*wr));
    };
    tw(5,  C1, -S1);
    tw(6,  HF, -HF);
    tw(7,  S1, -C1);
    tw(9,  HF, -HF);
    tw(11,-HF, -HF);
    tw(13, S1, -C1);
    tw(14,-HF, -HF);
    tw(15,-C1,  S1);
    cf z = c[10];                               // * (-i) fwd, (+i) inv
    c[10] = INV ? make_float2(-z.y, z.x) : make_float2(z.y, -z.x);
  }
#pragma unroll
  for (int r0 = 0; r0 < 4; ++r0){
    cf a = c[r0], b = c[4+r0], d = c[8+r0], e = c[12+r0];
    cf t0 = make_float2(a.x+d.x, a.y+d.y);
    cf t1 = make_float2(a.x-d.x, a.y-d.y);
    cf t2 = make_float2(b.x+e.x, b.y+e.y);
    cf t3 = make_float2(b.x-e.x, b.y-e.y);
    v[r0+0] = make_float2(t0.x+t2.x, t0.y+t2.y);
    v[r0+8] = make_float2(t0.x-t2.x, t0.y-t2.y);
    if (!INV){
      v[r0+4]  = make_float2(t1.x+t3.y, t1.y-t3.x);
      v[r0+12] = make_float2(t1.x-t3.y, t1.y+t3.x);
    } else {
      v[r0+4]  = make_float2(t1.x-t3.y, t1.y+t3.x);
      v[r0+12] = make_float2(t1.x+t3.y, t1.y-t3.x);
    }
  }
}

// multiply v[r] by e^{i*ang*r}, r=1..15 — tree build, dep depth ~5 (was 15)
__device__ __forceinline__ void twiddle_apply(cf* v, float ang){
  cf T[16];
  float s, c;
  __sincosf(ang, &s, &c);
  T[1] = make_float2(c, s);
#pragma unroll
  for (int r = 2; r < 16; ++r) T[r] = cmulf(T[r >> 1], T[r - (r >> 1)]);
#pragma unroll
  for (int r = 1; r < 16; ++r) v[r] = cmulf(v[r], T[r]);
}

__device__ __forceinline__ float fast_tanh(float x){
  float e = __expf(2.0f*x);
  return 1.0f - __fdividef(2.0f, e + 1.0f);
}

// ---------------- vandermonde: vand[p][l] = lambda_p^l (polar, f64 phase) -------------
__global__ void k_vand(const float* __restrict__ Lam, cf* __restrict__ vand){
  int gid = blockIdx.x*256 + threadIdx.x;        // 64*4096
  int p = gid >> 12;
  int l = gid & 4095;
  float lr = Lam[2*p], li = Lam[2*p+1];
  double r2 = (double)lr*(double)lr + (double)li*(double)li;
  double lg = 0.5 * log2(r2);                    // log2|lambda|
  double tt = atan2((double)li, (double)lr) * 0.15915494309189535; // turns
  double dl = (double)l;
  float mag = exp2f((float)(dl * lg));
  double ph = dl * tt;
  ph -= floor(ph);                               // frac turns in [0,1)
  float s, c;
  sincospif((float)(2.0*ph), &s, &c);
  vand[gid] = make_float2(mag*c, mag*s);
}

// ---------------- Kr[h][l] = Re( sum_p C[h,p]*B[p,h] * vand[p][l] ) -------------------
__global__ __launch_bounds__(512,4) void k_kr(
    const float* __restrict__ C, const float* __restrict__ Bb,
    const cf* __restrict__ vand, float* __restrict__ Kr){
  __shared__ cf Wsh[8][64];
  __shared__ cf Vt[16][512];     // 64 KiB tile
  const int t = threadIdx.x;
  const int hg = blockIdx.x >> 3;      // 32 h-groups of 8
  const int ls = blockIdx.x & 7;       // 8 l-slices of 512
  const int h0 = hg*8;
  const int l0 = ls*512;
  {
    int hl = t >> 6, p = t & 63;       // 512 entries
    int h = h0 + hl;
    cf cc = ((const cf*)C)[h*64 + p];
    cf bb = ((const cf*)Bb)[p*256 + h];
    Wsh[hl][p] = cmulf(cc, bb);
  }
  float acc[8] = {0,0,0,0,0,0,0,0};
  const int hl = t >> 6;               // wave id == local h
  const int lane = t & 63;
  for (int pc = 0; pc < 4; ++pc){
    __syncthreads();
    const float4* src = (const float4*)vand;  // row stride 2048 float4
#pragma unroll
    for (int j = 0; j < 8; ++j){
      int li = j*512 + t;              // 0..4095 float4s of tile
      int rp = li >> 8;                // tile row 0..15
      int colf4 = li & 255;
      ((float4*)Vt)[li] = src[(size_t)(pc*16 + rp)*2048 + (l0 >> 1) + colf4];
    }
    __syncthreads();
#pragma unroll
    for (int p = 0; p < 16; ++p){
      cf w = Wsh[hl][pc*16 + p];
#pragma unroll
      for (int j = 0; j < 8; ++j){
        cf vv = Vt[p][lane + 64*j];
        acc[j] = fmaf(w.x, vv.x, fmaf(-w.y, vv.y, acc[j]));
      }
    }
  }
  float* dst = Kr + (size_t)(h0 + hl)*NF + l0;
#pragma unroll
  for (int j = 0; j < 8; ++j) dst[lane + 64*j] = acc[j];
}

// ------------- forward FFT of two real kernel rows; emit M[h][idx] (digit-rev) --------
__global__ __launch_bounds__(256,4) void k_fftkr(
    const float* __restrict__ Kr, const float* __restrict__ D, cf* __restrict__ M){
  __shared__ cf X[4096];
  const int t = threadIdx.x;
  const int h0 = blockIdx.x*2, h1 = h0 + 1;
  const float* k0 = Kr + (size_t)h0*NF;
  const float* k1 = Kr + (size_t)h1*NF;
  cf v[16];
#pragma unroll
  for (int q = 0; q < 16; ++q) v[q] = make_float2(k0[t + 256*q], k1[t + 256*q]);
  dft16<0>(v);
  twiddle_apply(v, -(PI2F/4096.0f)*(float)t);
#pragma unroll
  for (int r = 0; r < 16; ++r) X[phys(t + 256*r)] = v[r];
  __syncthreads();
  const int base = ((t >> 4) << 8) + (t & 15);
#pragma unroll
  for (int q = 0; q < 16; ++q) v[q] = X[phys(base + 16*q)];
  dft16<0>(v);
  twiddle_apply(v, -(PI2F/256.0f)*(float)(t & 15));
#pragma unroll
  for (int r = 0; r < 16; ++r) X[phys(base + 16*r)] = v[r];
  __syncthreads();
#pragma unroll
  for (int q = 0; q < 16; ++q) v[q] = X[phys(16*t + q)];
  dft16<0>(v);
#pragma unroll
  for (int q = 0; q < 16; ++q) X[phys(16*t + q)] = v[q];
  __syncthreads();
  const float dd0 = D[h0*256 + h0];
  const float dd1 = D[h1*256 + h1];
  const float invN = 1.0f/4096.0f;
  cf* M0 = M + (size_t)h0*NF;
  cf* M1 = M + (size_t)h1*NF;
#pragma unroll
  for (int q = 0; q < 16; ++q){
    int idx = 16*t + q;
    cf Z = v[q];
    int k    = ((idx & 15) << 8) | (idx & 240) | (idx >> 8);   // true frequency
    int kc   = (4096 - k) & 4095;
    int pidx = ((kc & 15) << 8) | (kc & 240) | (kc >> 8);      // storage of N-k
    cf Zp = X[phys(pidx)];
    float KH0r = 0.5f*(Z.x + Zp.x);
    float KH0i = 0.5f*(Z.y - Zp.y);
    float KH1r = 0.5f*(Z.y + Zp.y);
    float KH1i = 0.5f*(Zp.x - Z.x);
    M0[idx] = make_float2((KH0r + dd0)*invN, KH0i*invN);
    M1[idx] = make_float2((KH1r + dd1)*invN, KH1i*invN);
  }
}

// ------------- main: z = u0 + i u1 ; FFT ; *M ; IFFT ; tanh ; store ------------------
__global__ __launch_bounds__(256,5) void k_main(
    const float* __restrict__ u, const cf* __restrict__ M, float* __restrict__ out){
  __shared__ cf X[4096];                 // exactly 32 KiB -> 5 blocks/CU
  const int t  = threadIdx.x;
  const int h  = blockIdx.x >> 3;
  const int pr = blockIdx.x & 7;
  const size_t row0 = ((size_t)pr*256 + h)*(size_t)NF;
  const size_t row1 = row0 + (size_t)8*256*NF;
  const float* u0 = u + row0;
  const float* u1 = u + row1;
  cf v[16];
  // stage 1 (m=4096, d=256) fused with global load
#pragma unroll
  for (int q = 0; q < 16; ++q) v[q] = make_float2(u0[t + 256*q], u1[t + 256*q]);
  dft16<0>(v);
  twiddle_apply(v, -(PI2F/4096.0f)*(float)t);
#pragma unroll
  for (int r = 0; r < 16; ++r) X[phys(t + 256*r)] = v[r];
  __syncthreads();
  // stage 2 (m=256, d=16)
  const int base = ((t >> 4) << 8) + (t & 15);
#pragma unroll
  for (int q = 0; q < 16; ++q) v[q] = X[phys(base + 16*q)];
  dft16<0>(v);
  twiddle_apply(v, -(PI2F/256.0f)*(float)(t & 15));
#pragma unroll
  for (int r = 0; r < 16; ++r) X[phys(base + 16*r)] = v[r];
  __syncthreads();
  // stage 3 (m=16, d=1) + pointwise + inverse stage 1, all in registers
#pragma unroll
  for (int q = 0; q < 16; ++q) v[q] = X[phys(16*t + q)];
  dft16<0>(v);
  {
    const float4* Mr = (const float4*)(M + (size_t)h*NF + 16*t);
#pragma unroll
    for (int j = 0; j < 8; ++j){
      float4 f = Mr[j];
      v[2*j]   = cmulf(v[2*j],   make_float2(f.x, f.y));
      v[2*j+1] = cmulf(v[2*j+1], make_float2(f.z, f.w));
    }
  }
  dft16<1>(v);
#pragma unroll
  for (int q = 0; q < 16; ++q) X[phys(16*t + q)] = v[q];
  __syncthreads();
  // inverse stage 2 (m=256, d=16)
#pragma unroll
  for (int q = 0; q < 16; ++q) v[q] = X[phys(base + 16*q)];
  twiddle_apply(v, (PI2F/256.0f)*(float)(t & 15));
  dft16<1>(v);
#pragma unroll
  for (int r = 0; r < 16; ++r) X[phys(base + 16*r)] = v[r];
  __syncthreads();
  // inverse stage 3 (m=4096, d=256) + epilogue
#pragma unroll
  for (int q = 0; q < 16; ++q) v[q] = X[phys(t + 256*q)];
  twiddle_apply(v, (PI2F/4096.0f)*(float)t);
  dft16<1>(v);
  float* o0 = out + row0;
  float* o1 = out + row1;
#pragma unroll
  for (int r = 0; r < 16; ++r){
    o0[t + 256*r] = fast_tanh(v[r].x);
    o1[t + 256*r] = fast_tanh(v[r].y);
  }
}

extern "C" void kernel_launch(void* const* d_in, const int* in_sizes, int n_in,
                              void* d_out, int out_size, void* d_ws, size_t ws_size,
                              hipStream_t stream){
  const float* u   = (const float*)d_in[0];
  const float* C   = (const float*)d_in[1];
  const float* D   = (const float*)d_in[2];
  const float* Bb  = (const float*)d_in[3];
  const float* Lam = (const float*)d_in[4];
  float* out = (float*)d_out;
  char* ws = (char*)d_ws;
  cf*    M    = (cf*)ws;                              // 8 MiB: [256][4096] cf, digit-rev order
  cf*    vand = (cf*)(ws + (size_t)(8u << 20));       // 2 MiB: [64][4096] cf
  float* Kr   = (float*)(ws + (size_t)(10u << 20));   // 4 MiB: [256][4096] f32

  k_vand <<<dim3(1024), dim3(256), 0, stream>>>(Lam, vand);
  k_kr   <<<dim3(256),  dim3(512), 0, stream>>>(C, Bb, vand, Kr);
  k_fftkr<<<dim3(128),  dim3(256), 0, stream>>>(Kr, D, M);
  k_main <<<dim3(2048), dim3(256), 0, stream>>>(u, M, out);
}

// Round 4
// 75.943 us; speedup vs baseline: 1.2631x; 1.2631x over previous
//
#include <hip/hip_runtime.h>
#include <cmath>

#define NF 4096
#define PI2F 6.2831853071795864769f

typedef float2 cf;

__device__ __forceinline__ cf cmulf(cf a, cf b){
  return make_float2(fmaf(a.x, b.x, -(a.y*b.y)), fmaf(a.x, b.y, a.y*b.x));
}

// Pair-preserving LDS swizzle: XOR bits 1..3 with bits 4..6.
// - keeps cf-pairs (16B) adjacent & aligned -> b128 vectorization survives
// - stride-256 / stride-16 scalar patterns: 16 bank-pairs x4 = b64 floor
// - per-thread contiguous-16 (as float4 slots 8t + (j ^ (t&7))): 8 bank-quads
//   x8 lanes = b128 floor (unswizzled would be ONE bank-quad x64 = 16-way)
// LDS stays exactly 4096 cf = 32 KiB -> 5 blocks/CU at <=102 VGPR.
__device__ __forceinline__ int phys(int i){ return i ^ (((i >> 4) & 7) << 1); }

// radix-16 DFT in registers; INV=0 forward (e^{-i}), INV=1 inverse (e^{+i}), unnormalized.
template<int INV>
__device__ __forceinline__ void dft16(cf* v){
  const float C1 = 0.9238795325112867f;
  const float S1 = 0.3826834323650898f;
  const float HF = 0.7071067811865476f;
  cf c[16];
#pragma unroll
  for (int q1 = 0; q1 < 4; ++q1){
    cf a = v[q1], b = v[q1+4], d = v[q1+8], e = v[q1+12];
    cf t0 = make_float2(a.x+d.x, a.y+d.y);
    cf t1 = make_float2(a.x-d.x, a.y-d.y);
    cf t2 = make_float2(b.x+e.x, b.y+e.y);
    cf t3 = make_float2(b.x-e.x, b.y-e.y);
    c[q1*4+0] = make_float2(t0.x+t2.x, t0.y+t2.y);
    c[q1*4+2] = make_float2(t0.x-t2.x, t0.y-t2.y);
    if (!INV){
      c[q1*4+1] = make_float2(t1.x+t3.y, t1.y-t3.x);   // t1 - i t3
      c[q1*4+3] = make_float2(t1.x-t3.y, t1.y+t3.x);   // t1 + i t3
    } else {
      c[q1*4+1] = make_float2(t1.x-t3.y, t1.y+t3.x);
      c[q1*4+3] = make_float2(t1.x+t3.y, t1.y-t3.x);
    }
  }
  // internal twiddles w16^{q1*r0} (conjugated for inverse)
  {
    auto tw = [&](int i, float wr, float wi){
      float wii = INV ? -wi : wi;
      cf z = c[i];
      c[i] = make_float2(fmaf(z.x, wr, -(z.y*wii)), fmaf(z.x, wii, z.y*wr));
    };
    tw(5,  C1, -S1);
    tw(6,  HF, -HF);
    tw(7,  S1, -C1);
    tw(9,  HF, -HF);
    tw(11,-HF, -HF);
    tw(13, S1, -C1);
    tw(14,-HF, -HF);
    tw(15,-C1,  S1);
    cf z = c[10];                               // * (-i) fwd, (+i) inv
    c[10] = INV ? make_float2(-z.y, z.x) : make_float2(z.y, -z.x);
  }
#pragma unroll
  for (int r0 = 0; r0 < 4; ++r0){
    cf a = c[r0], b = c[4+r0], d = c[8+r0], e = c[12+r0];
    cf t0 = make_float2(a.x+d.x, a.y+d.y);
    cf t1 = make_float2(a.x-d.x, a.y-d.y);
    cf t2 = make_float2(b.x+e.x, b.y+e.y);
    cf t3 = make_float2(b.x-e.x, b.y-e.y);
    v[r0+0] = make_float2(t0.x+t2.x, t0.y+t2.y);
    v[r0+8] = make_float2(t0.x-t2.x, t0.y-t2.y);
    if (!INV){
      v[r0+4]  = make_float2(t1.x+t3.y, t1.y-t3.x);
      v[r0+12] = make_float2(t1.x-t3.y, t1.y+t3.x);
    } else {
      v[r0+4]  = make_float2(t1.x-t3.y, t1.y+t3.x);
      v[r0+12] = make_float2(t1.x+t3.y, t1.y-t3.x);
    }
  }
}

// multiply v[r] by e^{i*ang*r}, r=1..15 — tree build, dep depth ~5
__device__ __forceinline__ void twiddle_apply(cf* v, float ang){
  cf T[16];
  float s, c;
  __sincosf(ang, &s, &c);
  T[1] = make_float2(c, s);
#pragma unroll
  for (int r = 2; r < 16; ++r) T[r] = cmulf(T[r >> 1], T[r - (r >> 1)]);
#pragma unroll
  for (int r = 1; r < 16; ++r) v[r] = cmulf(v[r], T[r]);
}

__device__ __forceinline__ float fast_tanh(float x){
  float e = __expf(2.0f*x);
  return 1.0f - __fdividef(2.0f, e + 1.0f);
}

// ---------------- vandermonde: vand[p][l] = lambda_p^l (polar, f64 phase) -------------
__global__ void k_vand(const float* __restrict__ Lam, cf* __restrict__ vand){
  int gid = blockIdx.x*256 + threadIdx.x;        // 64*4096
  int p = gid >> 12;
  int l = gid & 4095;
  float lr = Lam[2*p], li = Lam[2*p+1];
  double r2 = (double)lr*(double)lr + (double)li*(double)li;
  double lg = 0.5 * log2(r2);                    // log2|lambda|
  double tt = atan2((double)li, (double)lr) * 0.15915494309189535; // turns
  double dl = (double)l;
  float mag = exp2f((float)(dl * lg));
  double ph = dl * tt;
  ph -= floor(ph);                               // frac turns in [0,1)
  float s, c;
  sincospif((float)(2.0*ph), &s, &c);
  vand[gid] = make_float2(mag*c, mag*s);
}

// ---------------- Kr[h][l] = Re( sum_p C[h,p]*B[p,h] * vand[p][l] ) -------------------
__global__ __launch_bounds__(512,4) void k_kr(
    const float* __restrict__ C, const float* __restrict__ Bb,
    const cf* __restrict__ vand, float* __restrict__ Kr){
  __shared__ cf Wsh[8][64];
  __shared__ cf Vt[16][512];     // 64 KiB tile
  const int t = threadIdx.x;
  const int hg = blockIdx.x >> 3;      // 32 h-groups of 8
  const int ls = blockIdx.x & 7;       // 8 l-slices of 512
  const int h0 = hg*8;
  const int l0 = ls*512;
  {
    int hl = t >> 6, p = t & 63;       // 512 entries
    int h = h0 + hl;
    cf cc = ((const cf*)C)[h*64 + p];
    cf bb = ((const cf*)Bb)[p*256 + h];
    Wsh[hl][p] = cmulf(cc, bb);
  }
  float acc[8] = {0,0,0,0,0,0,0,0};
  const int hl = t >> 6;               // wave id == local h
  const int lane = t & 63;
  for (int pc = 0; pc < 4; ++pc){
    __syncthreads();
    const float4* src = (const float4*)vand;  // row stride 2048 float4
#pragma unroll
    for (int j = 0; j < 8; ++j){
      int li = j*512 + t;              // 0..4095 float4s of tile
      int rp = li >> 8;                // tile row 0..15
      int colf4 = li & 255;
      ((float4*)Vt)[li] = src[(size_t)(pc*16 + rp)*2048 + (l0 >> 1) + colf4];
    }
    __syncthreads();
#pragma unroll
    for (int p = 0; p < 16; ++p){
      cf w = Wsh[hl][pc*16 + p];
#pragma unroll
      for (int j = 0; j < 8; ++j){
        cf vv = Vt[p][lane + 64*j];
        acc[j] = fmaf(w.x, vv.x, fmaf(-w.y, vv.y, acc[j]));
      }
    }
  }
  float* dst = Kr + (size_t)(h0 + hl)*NF + l0;
#pragma unroll
  for (int j = 0; j < 8; ++j) dst[lane + 64*j] = acc[j];
}

// ------------- forward FFT of two real kernel rows; emit M[h][idx] (digit-rev) --------
__global__ __launch_bounds__(256,4) void k_fftkr(
    const float* __restrict__ Kr, const float* __restrict__ D, cf* __restrict__ M){
  __shared__ cf X[4096];
  const int t = threadIdx.x;
  const int h0 = blockIdx.x*2, h1 = h0 + 1;
  const float* k0 = Kr + (size_t)h0*NF;
  const float* k1 = Kr + (size_t)h1*NF;
  cf v[16];
#pragma unroll
  for (int q = 0; q < 16; ++q) v[q] = make_float2(k0[t + 256*q], k1[t + 256*q]);
  dft16<0>(v);
  twiddle_apply(v, -(PI2F/4096.0f)*(float)t);
#pragma unroll
  for (int r = 0; r < 16; ++r) X[phys(t + 256*r)] = v[r];
  __syncthreads();
  const int base = ((t >> 4) << 8) + (t & 15);
#pragma unroll
  for (int q = 0; q < 16; ++q) v[q] = X[phys(base + 16*q)];
  dft16<0>(v);
  twiddle_apply(v, -(PI2F/256.0f)*(float)(t & 15));
#pragma unroll
  for (int r = 0; r < 16; ++r) X[phys(base + 16*r)] = v[r];
  __syncthreads();
  {
    const int s3 = t & 7;
    const float4* X4 = (const float4*)X;
#pragma unroll
    for (int j = 0; j < 8; ++j){
      float4 f = X4[8*t + (j ^ s3)];
      v[2*j]   = make_float2(f.x, f.y);
      v[2*j+1] = make_float2(f.z, f.w);
    }
  }
  dft16<0>(v);
  {
    const int s3 = t & 7;
    float4* X4 = (float4*)X;
#pragma unroll
    for (int j = 0; j < 8; ++j)
      X4[8*t + (j ^ s3)] = make_float4(v[2*j].x, v[2*j].y, v[2*j+1].x, v[2*j+1].y);
  }
  __syncthreads();
  const float dd0 = D[h0*256 + h0];
  const float dd1 = D[h1*256 + h1];
  const float invN = 1.0f/4096.0f;
  cf* M0 = M + (size_t)h0*NF;
  cf* M1 = M + (size_t)h1*NF;
#pragma unroll
  for (int q = 0; q < 16; ++q){
    int idx = 16*t + q;
    cf Z = v[q];
    int k    = ((idx & 15) << 8) | (idx & 240) | (idx >> 8);   // true frequency
    int kc   = (4096 - k) & 4095;
    int pidx = ((kc & 15) << 8) | (kc & 240) | (kc >> 8);      // storage of N-k
    cf Zp = X[phys(pidx)];
    float KH0r = 0.5f*(Z.x + Zp.x);
    float KH0i = 0.5f*(Z.y - Zp.y);
    float KH1r = 0.5f*(Z.y + Zp.y);
    float KH1i = 0.5f*(Zp.x - Z.x);
    M0[idx] = make_float2((KH0r + dd0)*invN, KH0i*invN);
    M1[idx] = make_float2((KH1r + dd1)*invN, KH1i*invN);
  }
}

// ------------- main: z = u0 + i u1 ; FFT ; *M ; IFFT ; tanh ; store ------------------
__global__ __launch_bounds__(256,4) void k_main(
    const float* __restrict__ u, const cf* __restrict__ M, float* __restrict__ out){
  __shared__ cf X[4096];                 // exactly 32 KiB
  const int t  = threadIdx.x;
  const int h  = blockIdx.x >> 3;
  const int pr = blockIdx.x & 7;
  const size_t row0 = ((size_t)pr*256 + h)*(size_t)NF;
  const size_t row1 = row0 + (size_t)8*256*NF;
  const float* u0 = u + row0;
  const float* u1 = u + row1;
  cf v[16];
  // stage 1 (m=4096, d=256) fused with global load
#pragma unroll
  for (int q = 0; q < 16; ++q) v[q] = make_float2(u0[t + 256*q], u1[t + 256*q]);
  dft16<0>(v);
  twiddle_apply(v, -(PI2F/4096.0f)*(float)t);
#pragma unroll
  for (int r = 0; r < 16; ++r) X[phys(t + 256*r)] = v[r];
  __syncthreads();
  // stage 2 (m=256, d=16)
  const int base = ((t >> 4) << 8) + (t & 15);
#pragma unroll
  for (int q = 0; q < 16; ++q) v[q] = X[phys(base + 16*q)];
  dft16<0>(v);
  twiddle_apply(v, -(PI2F/256.0f)*(float)(t & 15));
#pragma unroll
  for (int r = 0; r < 16; ++r) X[phys(base + 16*r)] = v[r];
  __syncthreads();
  // stage 3 (m=16, d=1) + pointwise + inverse stage 1, all in registers.
  // explicit float4 LDS I/O: logical pair j lives at float4 slot 8t + (j ^ (t&7))
  const int s3 = t & 7;
  {
    const float4* X4 = (const float4*)X;
#pragma unroll
    for (int j = 0; j < 8; ++j){
      float4 f = X4[8*t + (j ^ s3)];
      v[2*j]   = make_float2(f.x, f.y);
      v[2*j+1] = make_float2(f.z, f.w);
    }
  }
  dft16<0>(v);
  {
    const float4* Mr = (const float4*)(M + (size_t)h*NF + 16*t);
#pragma unroll
    for (int j = 0; j < 8; ++j){
      float4 f = Mr[j];
      v[2*j]   = cmulf(v[2*j],   make_float2(f.x, f.y));
      v[2*j+1] = cmulf(v[2*j+1], make_float2(f.z, f.w));
    }
  }
  dft16<1>(v);
  {
    float4* X4 = (float4*)X;
#pragma unroll
    for (int j = 0; j < 8; ++j)
      X4[8*t + (j ^ s3)] = make_float4(v[2*j].x, v[2*j].y, v[2*j+1].x, v[2*j+1].y);
  }
  __syncthreads();
  // inverse stage 2 (m=256, d=16)
#pragma unroll
  for (int q = 0; q < 16; ++q) v[q] = X[phys(base + 16*q)];
  twiddle_apply(v, (PI2F/256.0f)*(float)(t & 15));
  dft16<1>(v);
#pragma unroll
  for (int r = 0; r < 16; ++r) X[phys(base + 16*r)] = v[r];
  __syncthreads();
  // inverse stage 3 (m=4096, d=256) + epilogue
#pragma unroll
  for (int q = 0; q < 16; ++q) v[q] = X[phys(t + 256*q)];
  twiddle_apply(v, (PI2F/4096.0f)*(float)t);
  dft16<1>(v);
  float* o0 = out + row0;
  float* o1 = out + row1;
#pragma unroll
  for (int r = 0; r < 16; ++r){
    o0[t + 256*r] = fast_tanh(v[r].x);
    o1[t + 256*r] = fast_tanh(v[r].y);
  }
}

extern "C" void kernel_launch(void* const* d_in, const int* in_sizes, int n_in,
                              void* d_out, int out_size, void* d_ws, size_t ws_size,
                              hipStream_t stream){
  const float* u   = (const float*)d_in[0];
  const float* C   = (const float*)d_in[1];
  const float* D   = (const float*)d_in[2];
  const float* Bb  = (const float*)d_in[3];
  const float* Lam = (const float*)d_in[4];
  float* out = (float*)d_out;
  char* ws = (char*)d_ws;
  cf*    M    = (cf*)ws;                              // 8 MiB: [256][4096] cf, digit-rev order
  cf*    vand = (cf*)(ws + (size_t)(8u << 20));       // 2 MiB: [64][4096] cf
  float* Kr   = (float*)(ws + (size_t)(10u << 20));   // 4 MiB: [256][4096] f32

  k_vand <<<dim3(1024), dim3(256), 0, stream>>>(Lam, vand);
  k_kr   <<<dim3(256),  dim3(512), 0, stream>>>(C, Bb, vand, Kr);
  k_fftkr<<<dim3(128),  dim3(256), 0, stream>>>(Kr, D, M);
  k_main <<<dim3(2048), dim3(256), 0, stream>>>(u, M, out);
}

// Round 5
// 72.548 us; speedup vs baseline: 1.3223x; 1.0468x over previous
//
#include <hip/hip_runtime.h>
#include <cmath>

#define NF 4096
#define PI2F 6.2831853071795864769f

typedef float2 cf;

__device__ __forceinline__ cf cmulf(cf a, cf b){
  return make_float2(fmaf(a.x, b.x, -(a.y*b.y)), fmaf(a.x, b.y, a.y*b.x));
}
__device__ __forceinline__ cf cadd(cf a, cf b){ return make_float2(a.x+b.x, a.y+b.y); }
__device__ __forceinline__ cf csub(cf a, cf b){ return make_float2(a.x-b.x, a.y-b.y); }

// additive pad: cf index i -> i + (i>>3). Strides 512/64/8/1 all land at or
// near the b64 bank floor. LDS = 4608 cf = 36 KiB -> 4 blocks/CU; with
// 512-thread blocks that is 4 x 8 = 32 waves/CU = the hardware cap.
__device__ __forceinline__ int phys(int i){ return i + (i >> 3); }

// base-8 digit reversal of a 12-bit index (storage idx <-> true frequency)
__device__ __forceinline__ int rev8(int i){
  return ((i & 7) << 9) | (((i >> 3) & 7) << 6) | (((i >> 6) & 7) << 3) | ((i >> 9) & 7);
}

// radix-8 DFT in registers; INV=0 forward (e^{-i}), INV=1 inverse (e^{+i}), unnormalized.
template<int INV>
__device__ __forceinline__ void dft8(cf* v){
  const float HF = 0.7071067811865476f;
  cf e0,e1,e2,e3,o0,o1,o2,o3;
  {
    cf t0 = cadd(v[0], v[4]);
    cf t1 = csub(v[0], v[4]);
    cf t2 = cadd(v[2], v[6]);
    cf t3 = csub(v[2], v[6]);
    e0 = cadd(t0,t2); e2 = csub(t0,t2);
    if (!INV){ e1 = make_float2(t1.x+t3.y, t1.y-t3.x); e3 = make_float2(t1.x-t3.y, t1.y+t3.x); }
    else     { e1 = make_float2(t1.x-t3.y, t1.y+t3.x); e3 = make_float2(t1.x+t3.y, t1.y-t3.x); }
  }
  {
    cf t0 = cadd(v[1], v[5]);
    cf t1 = csub(v[1], v[5]);
    cf t2 = cadd(v[3], v[7]);
    cf t3 = csub(v[3], v[7]);
    o0 = cadd(t0,t2); o2 = csub(t0,t2);
    if (!INV){ o1 = make_float2(t1.x+t3.y, t1.y-t3.x); o3 = make_float2(t1.x-t3.y, t1.y+t3.x); }
    else     { o1 = make_float2(t1.x-t3.y, t1.y+t3.x); o3 = make_float2(t1.x+t3.y, t1.y-t3.x); }
  }
  cf w1, w2, w3;
  if (!INV){
    w1 = make_float2(HF*(o1.x + o1.y), HF*(o1.y - o1.x));   // o1 * (HF,-HF)
    w2 = make_float2(o2.y, -o2.x);                          // o2 * (0,-1)
    w3 = make_float2(HF*(o3.y - o3.x), -HF*(o3.x + o3.y));  // o3 * (-HF,-HF)
  } else {
    w1 = make_float2(HF*(o1.x - o1.y), HF*(o1.y + o1.x));   // o1 * (HF,+HF)
    w2 = make_float2(-o2.y, o2.x);                          // o2 * (0,+1)
    w3 = make_float2(-HF*(o3.x + o3.y), HF*(o3.x - o3.y));  // o3 * (-HF,+HF)
  }
  v[0] = cadd(e0,o0); v[4] = csub(e0,o0);
  v[1] = cadd(e1,w1); v[5] = csub(e1,w1);
  v[2] = cadd(e2,w2); v[6] = csub(e2,w2);
  v[3] = cadd(e3,w3); v[7] = csub(e3,w3);
}

// v[r] *= e^{i*ang*r}, r=1..7 (tree build, dep depth 3)
__device__ __forceinline__ void twiddle8(cf* v, float ang){
  float s, c;
  __sincosf(ang, &s, &c);
  cf T1 = make_float2(c, s);
  cf T2 = cmulf(T1, T1);
  cf T3 = cmulf(T2, T1);
  cf T4 = cmulf(T2, T2);
  cf T5 = cmulf(T3, T2);
  cf T6 = cmulf(T3, T3);
  cf T7 = cmulf(T4, T3);
  v[1] = cmulf(v[1], T1); v[2] = cmulf(v[2], T2); v[3] = cmulf(v[3], T3);
  v[4] = cmulf(v[4], T4); v[5] = cmulf(v[5], T5); v[6] = cmulf(v[6], T6);
  v[7] = cmulf(v[7], T7);
}

__device__ __forceinline__ float fast_tanh(float x){
  float e = __expf(2.0f*x);
  return 1.0f - __fdividef(2.0f, e + 1.0f);
}

// ---------------- vandermonde: vand[p][l] = lambda_p^l (polar, f64 phase) -------------
__global__ void k_vand(const float* __restrict__ Lam, cf* __restrict__ vand){
  int gid = blockIdx.x*256 + threadIdx.x;        // 64*4096
  int p = gid >> 12;
  int l = gid & 4095;
  float lr = Lam[2*p], li = Lam[2*p+1];
  double r2 = (double)lr*(double)lr + (double)li*(double)li;
  double lg = 0.5 * log2(r2);                    // log2|lambda|
  double tt = atan2((double)li, (double)lr) * 0.15915494309189535; // turns
  double dl = (double)l;
  float mag = exp2f((float)(dl * lg));
  double ph = dl * tt;
  ph -= floor(ph);                               // frac turns in [0,1)
  float s, c;
  sincospif((float)(2.0*ph), &s, &c);
  vand[gid] = make_float2(mag*c, mag*s);
}

// ---------------- Kr[h][l] = Re( sum_p C[h,p]*B[p,h] * vand[p][l] ) -------------------
__global__ __launch_bounds__(512,4) void k_kr(
    const float* __restrict__ C, const float* __restrict__ Bb,
    const cf* __restrict__ vand, float* __restrict__ Kr){
  __shared__ cf Wsh[8][64];
  __shared__ cf Vt[16][512];     // 64 KiB tile
  const int t = threadIdx.x;
  const int hg = blockIdx.x >> 3;      // 32 h-groups of 8
  const int ls = blockIdx.x & 7;       // 8 l-slices of 512
  const int h0 = hg*8;
  const int l0 = ls*512;
  {
    int hl = t >> 6, p = t & 63;       // 512 entries
    int h = h0 + hl;
    cf cc = ((const cf*)C)[h*64 + p];
    cf bb = ((const cf*)Bb)[p*256 + h];
    Wsh[hl][p] = cmulf(cc, bb);
  }
  float acc[8] = {0,0,0,0,0,0,0,0};
  const int hl = t >> 6;               // wave id == local h
  const int lane = t & 63;
  for (int pc = 0; pc < 4; ++pc){
    __syncthreads();
    const float4* src = (const float4*)vand;  // row stride 2048 float4
#pragma unroll
    for (int j = 0; j < 8; ++j){
      int li = j*512 + t;              // 0..4095 float4s of tile
      int rp = li >> 8;                // tile row 0..15
      int colf4 = li & 255;
      ((float4*)Vt)[li] = src[(size_t)(pc*16 + rp)*2048 + (l0 >> 1) + colf4];
    }
    __syncthreads();
#pragma unroll
    for (int p = 0; p < 16; ++p){
      cf w = Wsh[hl][pc*16 + p];
#pragma unroll
      for (int j = 0; j < 8; ++j){
        cf vv = Vt[p][lane + 64*j];
        acc[j] = fmaf(w.x, vv.x, fmaf(-w.y, vv.y, acc[j]));
      }
    }
  }
  float* dst = Kr + (size_t)(h0 + hl)*NF + l0;
#pragma unroll
  for (int j = 0; j < 8; ++j) dst[lane + 64*j] = acc[j];
}

// ------------- forward FFT of two real kernel rows; emit M[h][idx] (digit-rev base 8) -
__global__ __launch_bounds__(512,4) void k_fftkr(
    const float* __restrict__ Kr, const float* __restrict__ D, cf* __restrict__ M){
  __shared__ cf X[4608];
  const int t = threadIdx.x;
  const int h0 = blockIdx.x*2, h1 = h0 + 1;
  const float* kr0 = Kr + (size_t)h0*NF;
  const float* kr1 = Kr + (size_t)h1*NF;
  cf v[8];
#pragma unroll
  for (int q = 0; q < 8; ++q) v[q] = make_float2(kr0[t + 512*q], kr1[t + 512*q]);
  dft8<0>(v);
  twiddle8(v, -(PI2F/4096.0f)*(float)t);
#pragma unroll
  for (int r = 0; r < 8; ++r) X[phys(t + 512*r)] = v[r];
  __syncthreads();
  const int b2 = ((t >> 6) << 9) | (t & 63);
#pragma unroll
  for (int q = 0; q < 8; ++q) v[q] = X[phys(b2 + 64*q)];
  dft8<0>(v);
  twiddle8(v, -(PI2F/512.0f)*(float)(t & 63));
#pragma unroll
  for (int r = 0; r < 8; ++r) X[phys(b2 + 64*r)] = v[r];
  __syncthreads();
  const int b3 = ((t >> 3) << 6) | (t & 7);
#pragma unroll
  for (int q = 0; q < 8; ++q) v[q] = X[phys(b3 + 8*q)];
  dft8<0>(v);
  twiddle8(v, -(PI2F/64.0f)*(float)(t & 7));
#pragma unroll
  for (int r = 0; r < 8; ++r) X[phys(b3 + 8*r)] = v[r];
  __syncthreads();
#pragma unroll
  for (int q = 0; q < 8; ++q) v[q] = X[phys(8*t + q)];
  dft8<0>(v);
#pragma unroll
  for (int q = 0; q < 8; ++q) X[phys(8*t + q)] = v[q];
  __syncthreads();
  const float dd0 = D[h0*256 + h0];
  const float dd1 = D[h1*256 + h1];
  const float invN = 1.0f/4096.0f;
  float4* M0f = (float4*)(M + (size_t)h0*NF);
  float4* M1f = (float4*)(M + (size_t)h1*NF);
#pragma unroll
  for (int j = 0; j < 4; ++j){
    cf e0[2], e1[2];
#pragma unroll
    for (int s = 0; s < 2; ++s){
      int idx = 8*t + 2*j + s;
      cf Z = v[2*j + s];
      int k    = rev8(idx);
      int kc   = (4096 - k) & 4095;
      int pidx = rev8(kc);
      cf Zp = X[phys(pidx)];
      e0[s] = make_float2((0.5f*(Z.x + Zp.x) + dd0)*invN, 0.5f*(Z.y - Zp.y)*invN);
      e1[s] = make_float2((0.5f*(Z.y + Zp.y) + dd1)*invN, 0.5f*(Zp.x - Z.x)*invN);
    }
    M0f[4*t + j] = make_float4(e0[0].x, e0[0].y, e0[1].x, e0[1].y);
    M1f[4*t + j] = make_float4(e1[0].x, e1[0].y, e1[1].x, e1[1].y);
  }
}

// ------------- main: z = u0 + i u1 ; FFT ; *M ; IFFT ; tanh ; store ------------------
__global__ __launch_bounds__(512,8) void k_main(
    const float* __restrict__ u, const cf* __restrict__ M, float* __restrict__ out){
  __shared__ cf X[4608];                 // 36 KiB
  const int t  = threadIdx.x;
  const int h  = blockIdx.x >> 3;
  const int pr = blockIdx.x & 7;
  const size_t row0 = ((size_t)pr*256 + h)*(size_t)NF;
  const size_t row1 = row0 + (size_t)8*256*NF;
  const float* u0 = u + row0;
  const float* u1 = u + row1;
  cf v[8];
  // fwd stage 1 (span 4096)
#pragma unroll
  for (int q = 0; q < 8; ++q) v[q] = make_float2(u0[t + 512*q], u1[t + 512*q]);
  dft8<0>(v);
  twiddle8(v, -(PI2F/4096.0f)*(float)t);
#pragma unroll
  for (int r = 0; r < 8; ++r) X[phys(t + 512*r)] = v[r];
  __syncthreads();
  // fwd stage 2 (span 512)
  const int b2 = ((t >> 6) << 9) | (t & 63);
#pragma unroll
  for (int q = 0; q < 8; ++q) v[q] = X[phys(b2 + 64*q)];
  dft8<0>(v);
  twiddle8(v, -(PI2F/512.0f)*(float)(t & 63));
#pragma unroll
  for (int r = 0; r < 8; ++r) X[phys(b2 + 64*r)] = v[r];
  __syncthreads();
  // fwd stage 3 (span 64)
  const int b3 = ((t >> 3) << 6) | (t & 7);
#pragma unroll
  for (int q = 0; q < 8; ++q) v[q] = X[phys(b3 + 8*q)];
  dft8<0>(v);
  twiddle8(v, -(PI2F/64.0f)*(float)(t & 7));
#pragma unroll
  for (int r = 0; r < 8; ++r) X[phys(b3 + 8*r)] = v[r];
  __syncthreads();
  // M loads issued before stage-4 LDS reads: global latency hides under LDS+dft8
  float4 mf0, mf1;
  {
    const float4* Mr = (const float4*)(M + (size_t)h*NF + 8*t);
    mf0 = Mr[0]; mf1 = Mr[1];
  }
  // fwd stage 4 (span 8, contiguous) + pointwise + inv stage 1, in registers
#pragma unroll
  for (int q = 0; q < 8; ++q) v[q] = X[phys(8*t + q)];
  dft8<0>(v);
  {
    const float4* Mr = (const float4*)(M + (size_t)h*NF + 8*t);
    float4 f2 = Mr[2], f3 = Mr[3];
    v[0] = cmulf(v[0], make_float2(mf0.x, mf0.y));
    v[1] = cmulf(v[1], make_float2(mf0.z, mf0.w));
    v[2] = cmulf(v[2], make_float2(mf1.x, mf1.y));
    v[3] = cmulf(v[3], make_float2(mf1.z, mf1.w));
    v[4] = cmulf(v[4], make_float2(f2.x, f2.y));
    v[5] = cmulf(v[5], make_float2(f2.z, f2.w));
    v[6] = cmulf(v[6], make_float2(f3.x, f3.y));
    v[7] = cmulf(v[7], make_float2(f3.z, f3.w));
  }
  dft8<1>(v);
#pragma unroll
  for (int q = 0; q < 8; ++q) X[phys(8*t + q)] = v[q];
  __syncthreads();
  // inv stage 3
#pragma unroll
  for (int r = 0; r < 8; ++r) v[r] = X[phys(b3 + 8*r)];
  twiddle8(v, (PI2F/64.0f)*(float)(t & 7));
  dft8<1>(v);
#pragma unroll
  for (int q = 0; q < 8; ++q) X[phys(b3 + 8*q)] = v[q];
  __syncthreads();
  // inv stage 2
#pragma unroll
  for (int r = 0; r < 8; ++r) v[r] = X[phys(b2 + 64*r)];
  twiddle8(v, (PI2F/512.0f)*(float)(t & 63));
  dft8<1>(v);
#pragma unroll
  for (int q = 0; q < 8; ++q) X[phys(b2 + 64*q)] = v[q];
  __syncthreads();
  // inv stage 1 + epilogue
#pragma unroll
  for (int r = 0; r < 8; ++r) v[r] = X[phys(t + 512*r)];
  twiddle8(v, (PI2F/4096.0f)*(float)t);
  dft8<1>(v);
  float* o0 = out + row0;
  float* o1 = out + row1;
#pragma unroll
  for (int q = 0; q < 8; ++q){
    o0[t + 512*q] = fast_tanh(v[q].x);
    o1[t + 512*q] = fast_tanh(v[q].y);
  }
}

extern "C" void kernel_launch(void* const* d_in, const int* in_sizes, int n_in,
                              void* d_out, int out_size, void* d_ws, size_t ws_size,
                              hipStream_t stream){
  const float* u   = (const float*)d_in[0];
  const float* C   = (const float*)d_in[1];
  const float* D   = (const float*)d_in[2];
  const float* Bb  = (const float*)d_in[3];
  const float* Lam = (const float*)d_in[4];
  float* out = (float*)d_out;
  char* ws = (char*)d_ws;
  cf*    M    = (cf*)ws;                              // 8 MiB: [256][4096] cf, digit-rev (base 8)
  cf*    vand = (cf*)(ws + (size_t)(8u << 20));       // 2 MiB: [64][4096] cf
  float* Kr   = (float*)(ws + (size_t)(10u << 20));   // 4 MiB: [256][4096] f32

  k_vand <<<dim3(1024), dim3(256), 0, stream>>>(Lam, vand);
  k_kr   <<<dim3(256),  dim3(512), 0, stream>>>(C, Bb, vand, Kr);
  k_fftkr<<<dim3(128),  dim3(512), 0, stream>>>(Kr, D, M);
  k_main <<<dim3(2048), dim3(512), 0, stream>>>(u, M, out);
}